// Round 10
// baseline (103.510 us; speedup 1.0000x reference)
//
#include <hip/hip_runtime.h>
#include <stdint.h>

#define NB 4
#define NT 2048
#define NC 1024
#define NH 64
#define NM (NB*NT)

typedef unsigned short u16;
typedef __bf16 bf16_t;
typedef float f32x4 __attribute__((ext_vector_type(4)));
typedef bf16_t bf16x8 __attribute__((ext_vector_type(8)));
typedef u16 u16x8 __attribute__((ext_vector_type(8)));
typedef u16 u16x4 __attribute__((ext_vector_type(4)));

__device__ __forceinline__ u16 f2b(float f) {
  return __builtin_bit_cast(u16, (bf16_t)f);
}

union FusedShm {
  float wtT[64][65];                                    // phase W: 16.6 KB
  struct { u16 A[2][32 * 64]; u16 B[2][192 * 64]; } pr; // phase P: 56 KB
  struct { u16 sP[4][16 * 64]; float mo[2][16][68]; float ml[2][16]; } at; // phase A: ~17 KB
};

// device-scope grid barrier: all blocks co-resident by construction
// (grid 256 = half of the 2-blocks/CU capacity from launch_bounds + 56KB LDS).
__device__ __forceinline__ void gridbar(int* c, int nb) {
  __syncthreads();
  if (threadIdx.x == 0) {
    __threadfence();                       // release: make phase writes visible
    atomicAdd(c, 1);
    while (atomicAdd(c, 0) < nb) __builtin_amdgcn_s_sleep(8);
    __threadfence();                       // acquire: see other blocks' writes
  }
  __syncthreads();
}

__global__ __launch_bounds__(256, 2) void fused_kernel(const float* __restrict__ x,
                                                       const float* __restrict__ Wq,
                                                       const float* __restrict__ Wk,
                                                       const float* __restrict__ Wv,
                                                       u16* __restrict__ wt,
                                                       u16* __restrict__ qo,
                                                       u16* __restrict__ ko,
                                                       u16* __restrict__ vto,
                                                       float* __restrict__ out,
                                                       int* __restrict__ cnt) {
  __shared__ FusedShm shm;
  const int bid = blockIdx.x;
  const int tid = threadIdx.x;
  const int lane = tid & 63;
  const int g = lane >> 4;
  const int li = lane & 15;

  // ================= Phase W: Wq/Wk/Wv [1024][64] f32 -> WT [3][64][1024] bf16
  if (bid < 48) {
    const int m = bid >> 4;
    const int kt = bid & 15;
    const int k0 = kt * 64;
    const float* W = (m == 0) ? Wq : (m == 1) ? Wk : Wv;
    {
      const int r = tid >> 2, c4 = tid & 3;
      #pragma unroll
      for (int j = 0; j < 4; ++j) {
        const float4 f = *(const float4*)(W + (size_t)(k0 + r) * NH + c4 * 16 + j * 4);
        shm.wtT[r][c4 * 16 + j * 4 + 0] = f.x;
        shm.wtT[r][c4 * 16 + j * 4 + 1] = f.y;
        shm.wtT[r][c4 * 16 + j * 4 + 2] = f.z;
        shm.wtT[r][c4 * 16 + j * 4 + 3] = f.w;
      }
    }
    __syncthreads();
    const int n = tid >> 2, kc = tid & 3;
    u16x8 a, b;
    #pragma unroll
    for (int j = 0; j < 8; ++j) a[j] = f2b(shm.wtT[kc * 16 + j][n]);
    #pragma unroll
    for (int j = 0; j < 8; ++j) b[j] = f2b(shm.wtT[kc * 16 + 8 + j][n]);
    u16* dst = wt + ((size_t)(m * 64 + n)) * NC + k0 + kc * 16;
    *(u16x8*)dst = a;
    *(u16x8*)(dst + 8) = b;
  }
  gridbar(cnt + 0, (int)gridDim.x);

  // ================= Phase P: QKV projection, BM=32, double-buffered
  {
    const int wv4 = tid >> 6;        // 0..3
    const int wr = wv4 & 1;          // row subtile
    const int wh = wv4 >> 1;         // n half
    const int row0 = bid * 32;

    const f32x4 zero = {0.f, 0.f, 0.f, 0.f};
    f32x4 acc[6];
    #pragma unroll
    for (int i = 0; i < 6; ++i) acc[i] = zero;

    const int r = tid >> 3;          // 0..31 staging row
    const int fc = tid & 7;          // 8-float chunk
    const float* ap = x + (size_t)(row0 + r) * NC + fc * 8;

    float4 a0, a1;
    u16x8 bR[6];

    // prologue: stage buf0
    a0 = *(const float4*)(ap);
    a1 = *(const float4*)(ap + 4);
    #pragma unroll
    for (int it = 0; it < 6; ++it) {
      const int cid = it * 256 + tid;
      bR[it] = *(const u16x8*)(wt + (size_t)(cid >> 3) * NC + (cid & 7) * 8);
    }
    {
      u16x8 u;
      u[0]=f2b(a0.x); u[1]=f2b(a0.y); u[2]=f2b(a0.z); u[3]=f2b(a0.w);
      u[4]=f2b(a1.x); u[5]=f2b(a1.y); u[6]=f2b(a1.z); u[7]=f2b(a1.w);
      *(u16x8*)&shm.pr.A[0][r * 64 + ((fc ^ (r & 7)) * 8)] = u;
    }
    #pragma unroll
    for (int it = 0; it < 6; ++it) {
      const int cid = it * 256 + tid;
      const int n = cid >> 3, c = cid & 7;
      *(u16x8*)&shm.pr.B[0][n * 64 + ((c ^ (n & 7)) * 8)] = bR[it];
    }
    __syncthreads();

    for (int kt = 0; kt < 16; ++kt) {
      const int cur = kt & 1;
      const int k1 = (kt + 1) * 64;
      if (kt < 15) {
        a0 = *(const float4*)(ap + k1);
        a1 = *(const float4*)(ap + k1 + 4);
        #pragma unroll
        for (int it = 0; it < 6; ++it) {
          const int cid = it * 256 + tid;
          bR[it] = *(const u16x8*)(wt + (size_t)(cid >> 3) * NC + k1 + (cid & 7) * 8);
        }
      }
      #pragma unroll
      for (int ks = 0; ks < 2; ++ks) {
        const int ar = wr * 16 + li;
        const bf16x8 a = *(const bf16x8*)&shm.pr.A[cur][ar * 64 + (((ks * 4 + g) ^ (ar & 7)) * 8)];
        #pragma unroll
        for (int f6 = 0; f6 < 6; ++f6) {
          const int n = (wh * 6 + f6) * 16 + li;
          const bf16x8 b = *(const bf16x8*)&shm.pr.B[cur][n * 64 + (((ks * 4 + g) ^ (n & 7)) * 8)];
          acc[f6] = __builtin_amdgcn_mfma_f32_16x16x32_bf16(a, b, acc[f6], 0, 0, 0);
        }
      }
      if (kt < 15) {
        u16x8 u;
        u[0]=f2b(a0.x); u[1]=f2b(a0.y); u[2]=f2b(a0.z); u[3]=f2b(a0.w);
        u[4]=f2b(a1.x); u[5]=f2b(a1.y); u[6]=f2b(a1.z); u[7]=f2b(a1.w);
        *(u16x8*)&shm.pr.A[cur ^ 1][r * 64 + ((fc ^ (r & 7)) * 8)] = u;
        #pragma unroll
        for (int it = 0; it < 6; ++it) {
          const int cid = it * 256 + tid;
          const int n = cid >> 3, c = cid & 7;
          *(u16x8*)&shm.pr.B[cur ^ 1][n * 64 + ((c ^ (n & 7)) * 8)] = bR[it];
        }
      }
      __syncthreads();
    }

    // epilogue: C/D layout col=lane&15, row=(lane>>4)*4+reg; vto tile-blocked
    const int rr0 = row0 + wr * 16 + g * 4;
    #pragma unroll
    for (int f6 = 0; f6 < 6; ++f6) {
      const int fn = wh * 6 + f6;
      if (fn < 4) {
        #pragma unroll
        for (int i = 0; i < 4; ++i)
          qo[(size_t)(rr0 + i) * NH + fn * 16 + li] = f2b(acc[f6][i]);
      } else if (fn < 8) {
        #pragma unroll
        for (int i = 0; i < 4; ++i)
          ko[(size_t)(rr0 + i) * NH + (fn - 4) * 16 + li] = f2b(acc[f6][i]);
      } else {
        u16x4 pv;
        #pragma unroll
        for (int i = 0; i < 4; ++i) pv[i] = f2b(acc[f6][i]);
        const int hs = (fn - 8) * 16 + li;
        const int bidx = rr0 >> 11;
        const int tt = rr0 & 2047;
        const int tile = tt >> 6, off = tt & 63;
        *(u16x4*)&vto[(((size_t)(bidx * 32 + tile) * 64) + hs) * 64 + off] = pv;
      }
    }
  }
  gridbar(cnt + 1, (int)gridDim.x);

  // ================= Phase A: attention; block=(jt,bb); waves: qsub x (kv mod 2);
  // static softmax, 2-deep register pipeline, in-block exact merge, direct out.
  {
    const int wv4 = tid >> 6;
    const int qsub = wv4 & 1;
    const int ss = wv4 >> 1;         // kv split 0..1
    const int jt = bid & 63;
    const int bb = bid >> 6;         // 0..3
    const size_t bt0 = (size_t)bb * NT;
    const int q0w = jt * 32 + qsub * 16;

    bf16x8 aq[2];
    #pragma unroll
    for (int ks = 0; ks < 2; ++ks)
      aq[ks] = *(const bf16x8*)(qo + (bt0 + q0w + li) * NH + ks * 32 + g * 8);

    const f32x4 zero = {0.f, 0.f, 0.f, 0.f};
    f32x4 o[4];
    float lsum[4];
    #pragma unroll
    for (int i = 0; i < 4; ++i) { o[i] = zero; lsum[i] = 0.f; }

    const int nkv = jt / 2 + 1;

    auto loadTile = [&](bf16x8 (&kf)[2][4], bf16x8 (&vf)[2][4], int t) {
      const int kv0 = t * 64;
      #pragma unroll
      for (int ks = 0; ks < 2; ++ks)
        #pragma unroll
        for (int fn = 0; fn < 4; ++fn) {
          kf[ks][fn] = *(const bf16x8*)(ko + (bt0 + kv0 + fn * 16 + li) * NH + ks * 32 + g * 8);
          vf[ks][fn] = *(const bf16x8*)(vto + (((size_t)(bb * 32 + t) * 64) + fn * 16 + li) * 64 + ks * 32 + g * 8);
        }
    };

    auto computeTile = [&](bf16x8 (&kf)[2][4], bf16x8 (&vf)[2][4], int t) {
      const int kv0 = t * 64;
      f32x4 sc[4];
      #pragma unroll
      for (int fn = 0; fn < 4; ++fn) sc[fn] = zero;
      #pragma unroll
      for (int ks = 0; ks < 2; ++ks)
        #pragma unroll
        for (int fn = 0; fn < 4; ++fn)
          sc[fn] = __builtin_amdgcn_mfma_f32_16x16x32_bf16(aq[ks], kf[ks][fn], sc[fn], 0, 0, 0);

      const bool needmask = (kv0 + 63 > q0w);
      #pragma unroll
      for (int fn = 0; fn < 4; ++fn) {
        #pragma unroll
        for (int i = 0; i < 4; ++i) {
          float v = sc[fn][i] * 0.125f;
          if (needmask && (kv0 + fn * 16 + li > q0w + g * 4 + i)) v = -1e30f;
          const float e = __expf(v);
          lsum[i] += e;
          const int ql = g * 4 + i;
          const int kv = fn * 16 + li;
          shm.at.sP[wv4][ql * 64 + (((kv >> 3) ^ (ql & 7)) * 8) + (kv & 7)] = f2b(e);
        }
      }
      #pragma unroll
      for (int ks = 0; ks < 2; ++ks) {
        const bf16x8 pa = *(const bf16x8*)&shm.at.sP[wv4][li * 64 + (((ks * 4 + g) ^ (li & 7)) * 8)];
        #pragma unroll
        for (int fn = 0; fn < 4; ++fn)
          o[fn] = __builtin_amdgcn_mfma_f32_16x16x32_bf16(pa, vf[ks][fn], o[fn], 0, 0, 0);
      }
    };

    bf16x8 kA[2][4], vA[2][4], kB[2][4], vB[2][4];
    int t = ss;
    if (t < nkv) {
      loadTile(kA, vA, t);
      while (true) {
        const int tB = t + 2;
        if (tB < nkv) loadTile(kB, vB, tB);
        computeTile(kA, vA, t);
        if (tB >= nkv) break;
        const int tA = tB + 2;
        if (tA < nkv) loadTile(kA, vA, tA);
        computeTile(kB, vB, tB);
        if (tA >= nkv) break;
        t = tA;
      }
    }

    // row-reduce l within 16-lane groups
    #pragma unroll
    for (int i = 0; i < 4; ++i) {
      float l = lsum[i];
      l += __shfl_xor(l, 1);
      l += __shfl_xor(l, 2);
      l += __shfl_xor(l, 4);
      l += __shfl_xor(l, 8);
      lsum[i] = l;
    }

    // in-block merge of the two kv-splits (exact fp32 adds), write out
    if (ss == 1) {
      #pragma unroll
      for (int fn = 0; fn < 4; ++fn)
        #pragma unroll
        for (int i = 0; i < 4; ++i)
          shm.at.mo[qsub][g * 4 + i][fn * 16 + li] = o[fn][i];
      if (li == 0) {
        #pragma unroll
        for (int i = 0; i < 4; ++i) shm.at.ml[qsub][g * 4 + i] = lsum[i];
      }
    }
    __syncthreads();
    if (ss == 0) {
      #pragma unroll
      for (int i = 0; i < 4; ++i) lsum[i] += shm.at.ml[qsub][g * 4 + i];
      #pragma unroll
      for (int fn = 0; fn < 4; ++fn) {
        #pragma unroll
        for (int i = 0; i < 4; ++i) {
          const float v = o[fn][i] + shm.at.mo[qsub][g * 4 + i][fn * 16 + li];
          out[(bt0 + q0w + g * 4 + i) * NH + fn * 16 + li] = v / lsum[i];
        }
      }
    }
  }
}

extern "C" void kernel_launch(void* const* d_in, const int* in_sizes, int n_in,
                              void* d_out, int out_size, void* d_ws, size_t ws_size,
                              hipStream_t stream) {
  (void)in_sizes; (void)n_in; (void)out_size; (void)ws_size;
  const float* x  = (const float*)d_in[0];
  const float* Wq = (const float*)d_in[1];
  const float* Wk = (const float*)d_in[2];
  const float* Wv = (const float*)d_in[3];
  float* out = (float*)d_out;
  char* ws = (char*)d_ws;
  u16* qb  = (u16*)(ws);                        // 1 MB   : q bf16 [8192][64]
  u16* kb  = (u16*)(ws + (1u << 20));           // 1 MB   : k bf16 [8192][64]
  u16* vtb = (u16*)(ws + (2u << 20));           // 1 MB   : v^T bf16 tiled [4][32][64][64]
  u16* wtb = (u16*)(ws + (3u << 20));           // 384 KB : WT bf16 [3][64][1024]
  int* cnt = (int*)(ws + (3u << 20) + (512u << 10)); // 2 ints: grid barrier counters

  hipMemsetAsync(cnt, 0, 2 * sizeof(int), stream);
  hipLaunchKernelGGL(fused_kernel, dim3(256), dim3(256), 0, stream,
                     x, Wq, Wk, Wv, wtb, qb, kb, vtb, out, cnt);
}

// Round 11
// 56.873 us; speedup vs baseline: 1.8200x; 1.8200x over previous
//
#include <hip/hip_runtime.h>
#include <stdint.h>

#define NB 4
#define NT 2048
#define NC 1024
#define NH 64
#define NM (NB*NT)

typedef unsigned short u16;
typedef unsigned int u32;
typedef __bf16 bf16_t;
typedef float f32x4 __attribute__((ext_vector_type(4)));
typedef bf16_t bf16x8 __attribute__((ext_vector_type(8)));
typedef u16 u16x8 __attribute__((ext_vector_type(8)));
typedef u16 u16x4 __attribute__((ext_vector_type(4)));

__device__ __forceinline__ u16 f2b(float f) {
  return __builtin_bit_cast(u16, (bf16_t)f);
}

// async global->LDS 16B: LDS dest is WAVE-UNIFORM base + lane*16 (m104);
// per-lane swizzle goes into the GLOBAL source address (m173).
__device__ __forceinline__ void gl16(const void* g, void* l) {
  __builtin_amdgcn_global_load_lds(
      (const __attribute__((address_space(1))) u32*)g,
      (__attribute__((address_space(3))) u32*)l, 16, 0, 0);
}

// ---------------- Wq/Wk/Wv [1024][64] f32 -> WT [3][64][1024] bf16 (transposed)
__global__ __launch_bounds__(256) void wt_kernel(const float* __restrict__ Wq,
                                                 const float* __restrict__ Wk,
                                                 const float* __restrict__ Wv,
                                                 u16* __restrict__ wt) {
  __shared__ float t[64][65];
  const int m = blockIdx.x >> 4;
  const int kt = blockIdx.x & 15;
  const int k0 = kt * 64;
  const float* W = (m == 0) ? Wq : (m == 1) ? Wk : Wv;
  {
    const int r = threadIdx.x >> 2, c4 = threadIdx.x & 3;
    #pragma unroll
    for (int j = 0; j < 4; ++j) {
      const float4 f = *(const float4*)(W + (size_t)(k0 + r) * NH + c4 * 16 + j * 4);
      t[r][c4 * 16 + j * 4 + 0] = f.x;
      t[r][c4 * 16 + j * 4 + 1] = f.y;
      t[r][c4 * 16 + j * 4 + 2] = f.z;
      t[r][c4 * 16 + j * 4 + 3] = f.w;
    }
  }
  __syncthreads();
  const int n = threadIdx.x >> 2, kc = threadIdx.x & 3;
  u16x8 a, b;
  #pragma unroll
  for (int j = 0; j < 8; ++j) a[j] = f2b(t[kc * 16 + j][n]);
  #pragma unroll
  for (int j = 0; j < 8; ++j) b[j] = f2b(t[kc * 16 + 8 + j][n]);
  u16* dst = wt + ((size_t)(m * 64 + n)) * NC + k0 + kc * 16;
  *(u16x8*)dst = a;
  *(u16x8*)(dst + 8) = b;
}

// ---------------- fused QKV projection: global_load_lds double-buffered (m97 pattern)
// 512 blocks x 256 thr (2/CU), BM=16; 4 waves = 4 N-quarters (48 cols).
// A staged as fp32 (swizzled src), B bf16 (swizzled src). One barrier per K-step.
__global__ __launch_bounds__(256, 2) void proj_kernel(const float* __restrict__ x,
                                                      const u16* __restrict__ wt,
                                                      u16* __restrict__ qo,
                                                      u16* __restrict__ ko,
                                                      u16* __restrict__ vto) {
  __shared__ float fA[2][16 * 64];   // 4KB each
  __shared__ u16 sB[2][192 * 64];    // 24KB each
  const int tid = threadIdx.x;
  const int lane = tid & 63;
  const int w = tid >> 6;
  const int g = lane >> 4;
  const int li = lane & 15;
  const int row0 = blockIdx.x * 16;
  const int wbase = tid & 0xC0;      // wv*64, wave-uniform

  const f32x4 zero = {0.f, 0.f, 0.f, 0.f};
  f32x4 acc[3];
  #pragma unroll
  for (int i = 0; i < 3; ++i) acc[i] = zero;

  // staging source coordinates
  const int ar = tid >> 4;           // A row 0..15
  const int ac = tid & 15;           // A chunk 0..15 (16B = 4 f32)
  const float* asrc0 = x + (size_t)(row0 + ar) * NC + ((ac ^ (ar & 7)) * 4);

  auto stage = [&](int kt, int nxt) {
    const int k0 = kt * 64;
    gl16(asrc0 + k0, (char*)fA[nxt] + wbase * 16);
    #pragma unroll
    for (int j = 0; j < 6; ++j) {
      const int cid = j * 256 + tid;
      const int n = cid >> 3, c = cid & 7;
      gl16(wt + (size_t)n * NC + k0 + ((c ^ (n & 7)) * 8),
           (char*)sB[nxt] + (j * 256 + wbase) * 16);
    }
  };

  stage(0, 0);
  __syncthreads();

  for (int kt = 0; kt < 16; ++kt) {
    const int cur = kt & 1;
    if (kt < 15) stage(kt + 1, cur ^ 1);
    #pragma unroll
    for (int ks = 0; ks < 2; ++ks) {
      const int c0 = ks * 8 + g * 2;
      const f32x4 a0 = *(const f32x4*)&fA[cur][li * 64 + ((c0 ^ (li & 7)) * 4)];
      const f32x4 a1 = *(const f32x4*)&fA[cur][li * 64 + (((c0 + 1) ^ (li & 7)) * 4)];
      bf16x8 a;
      a[0]=(bf16_t)a0.x; a[1]=(bf16_t)a0.y; a[2]=(bf16_t)a0.z; a[3]=(bf16_t)a0.w;
      a[4]=(bf16_t)a1.x; a[5]=(bf16_t)a1.y; a[6]=(bf16_t)a1.z; a[7]=(bf16_t)a1.w;
      #pragma unroll
      for (int f = 0; f < 3; ++f) {
        const int n = (w * 3 + f) * 16 + li;
        const bf16x8 b = *(const bf16x8*)&sB[cur][n * 64 + (((ks * 4 + g) ^ (n & 7)) * 8)];
        acc[f] = __builtin_amdgcn_mfma_f32_16x16x32_bf16(a, b, acc[f], 0, 0, 0);
      }
    }
    __syncthreads();
  }

  // epilogue: C/D layout col=lane&15, row=(lane>>4)*4+reg; vto tile-blocked
  const int rr0 = row0 + g * 4;
  #pragma unroll
  for (int f = 0; f < 3; ++f) {
    const int fn = w * 3 + f;
    if (fn < 4) {
      #pragma unroll
      for (int i = 0; i < 4; ++i)
        qo[(size_t)(rr0 + i) * NH + fn * 16 + li] = f2b(acc[f][i]);
    } else if (fn < 8) {
      #pragma unroll
      for (int i = 0; i < 4; ++i)
        ko[(size_t)(rr0 + i) * NH + (fn - 4) * 16 + li] = f2b(acc[f][i]);
    } else {
      u16x4 pv;
      #pragma unroll
      for (int i = 0; i < 4; ++i) pv[i] = f2b(acc[f][i]);
      const int hs = (fn - 8) * 16 + li;
      const int bidx = rr0 >> 11;
      const int tt = rr0 & 2047;
      const int tile = tt >> 6, off = tt & 63;
      *(u16x4*)&vto[(((size_t)(bidx * 32 + tile) * 64) + hs) * 64 + off] = pv;
    }
  }
}

// ---------------- attention: q-tile=16 rows, 4 waves = 4 kv-quarters per 64-kv tile,
// K/V via global_load_lds double-buffer (1 barrier/tile), static softmax,
// wave-local zero-padded P (PV k=32 MFMA, half zeros), in-block exact merge.
union AttnShm {
  struct { u16 K[2][64 * 64]; u16 V[2][64 * 64]; } st;   // 32KB staging
  struct { float mo[4][16][68]; float ml[4][16]; } mg;   // merge (aliased)
};

__global__ __launch_bounds__(256, 2) void attn_kernel(const u16* __restrict__ qg,
                                                      const u16* __restrict__ kg,
                                                      const u16* __restrict__ vtg,
                                                      float* __restrict__ out) {
  __shared__ AttnShm shm;
  __shared__ u16 sP[4][16 * 32];     // per-wave padded P [16 rows][32 cols], 1KB each
  const int tid = threadIdx.x;
  const int lane = tid & 63;
  const int wv = tid >> 6;           // kv quarter 0..3
  const int g = lane >> 4;
  const int li = lane & 15;
  const int wbase = tid & 0xC0;
  const int b = blockIdx.x;
  const int bb = b >> 7;
  const int jt2 = (((b & 127) * 37) + bb * 53) & 127;   // scrambled for CU balance
  const size_t bt0 = (size_t)bb * NT;
  const int q0 = jt2 * 16;
  const int nkv = (jt2 >> 2) + 1;

  // zero P (pads stay zero forever)
  {
    u16x8 z = {0, 0, 0, 0, 0, 0, 0, 0};
    *(u16x8*)(((u16*)sP) + tid * 8) = z;
  }

  // Q a-frags (row = li, one-time)
  bf16x8 aq[2];
  #pragma unroll
  for (int ks = 0; ks < 2; ++ks)
    aq[ks] = *(const bf16x8*)(qg + (bt0 + q0 + li) * NH + ks * 32 + g * 8);

  const f32x4 zero = {0.f, 0.f, 0.f, 0.f};
  f32x4 o[4];
  float lsum[4];
  #pragma unroll
  for (int i = 0; i < 4; ++i) { o[i] = zero; lsum[i] = 0.f; }

  auto stage = [&](int t, int nxt) {
    #pragma unroll
    for (int j = 0; j < 2; ++j) {
      const int cid = j * 256 + tid;
      const int n = cid >> 3, c = cid & 7;
      const int sc = (c ^ (n & 7)) * 8;
      gl16(kg + (bt0 + (size_t)t * 64 + n) * NH + sc,
           (char*)shm.st.K[nxt] + (j * 256 + wbase) * 16);
      gl16(vtg + (((size_t)(bb * 32 + t) * 64) + n) * NH + sc,
           (char*)shm.st.V[nxt] + (j * 256 + wbase) * 16);
    }
  };

  stage(0, 0);
  __syncthreads();

  for (int t = 0; t < nkv; ++t) {
    const int cur = t & 1;
    if (t + 1 < nkv) stage(t + 1, cur ^ 1);

    // QK^T: this wave's 16 kv cols
    f32x4 s = zero;
    #pragma unroll
    for (int ks = 0; ks < 2; ++ks) {
      const int n = wv * 16 + li;
      const bf16x8 bk = *(const bf16x8*)&shm.st.K[cur][n * 64 + (((ks * 4 + g) ^ (n & 7)) * 8)];
      s = __builtin_amdgcn_mfma_f32_16x16x32_bf16(aq[ks], bk, s, 0, 0, 0);
    }

    // static softmax: P = exp(s/8), causal mask (predicated, cheap)
    const int kvg = t * 64 + wv * 16 + li;
    #pragma unroll
    for (int i = 0; i < 4; ++i) {
      const int q = q0 + g * 4 + i;
      float v = s[i] * 0.125f;
      if (kvg > q) v = -1e30f;
      const float e = __expf(v);
      lsum[i] += e;
      const int c = (wv & 1) * 2 + (li >> 3);
      sP[wv][q * 0 + (g * 4 + i) * 32 + ((c ^ ((g * 4 + i) & 3)) * 8) + (li & 7)] = f2b(e);
    }

    // PV: k=32 window (quarter pair), wave-local P a-frag (1 read), 4 hs-frags
    const bf16x8 pa = *(const bf16x8*)&sP[wv][li * 32 + ((g ^ (li & 3)) * 8)];
    const int sch = (wv >> 1) * 4 + g;
    #pragma unroll
    for (int fn = 0; fn < 4; ++fn) {
      const int n = fn * 16 + li;
      const bf16x8 bv = *(const bf16x8*)&shm.st.V[cur][n * 64 + ((sch ^ (n & 7)) * 8)];
      o[fn] = __builtin_amdgcn_mfma_f32_16x16x32_bf16(pa, bv, o[fn], 0, 0, 0);
    }
    __syncthreads();
  }

  // row-sum l within 16-lane groups (cols of this wave's quarter)
  #pragma unroll
  for (int i = 0; i < 4; ++i) {
    float l = lsum[i];
    l += __shfl_xor(l, 1);
    l += __shfl_xor(l, 2);
    l += __shfl_xor(l, 4);
    l += __shfl_xor(l, 8);
    lsum[i] = l;
  }

  // in-block merge of the 4 kv-quarter partials (aliases staging LDS)
  #pragma unroll
  for (int fn = 0; fn < 4; ++fn)
    #pragma unroll
    for (int i = 0; i < 4; ++i)
      shm.mg.mo[wv][g * 4 + i][fn * 16 + li] = o[fn][i];
  if (li == 0) {
    #pragma unroll
    for (int i = 0; i < 4; ++i) shm.mg.ml[wv][g * 4 + i] = lsum[i];
  }
  __syncthreads();

  {
    const int col = tid & 63;
    const int r0 = (tid >> 6) * 4;
    #pragma unroll
    for (int i = 0; i < 4; ++i) {
      const int r = r0 + i;
      const float L = shm.mg.ml[0][r] + shm.mg.ml[1][r] + shm.mg.ml[2][r] + shm.mg.ml[3][r];
      const float v = shm.mg.mo[0][r][col] + shm.mg.mo[1][r][col]
                    + shm.mg.mo[2][r][col] + shm.mg.mo[3][r][col];
      out[(bt0 + q0 + r) * NH + col] = v / L;
    }
  }
}

extern "C" void kernel_launch(void* const* d_in, const int* in_sizes, int n_in,
                              void* d_out, int out_size, void* d_ws, size_t ws_size,
                              hipStream_t stream) {
  (void)in_sizes; (void)n_in; (void)out_size; (void)ws_size;
  const float* x  = (const float*)d_in[0];
  const float* Wq = (const float*)d_in[1];
  const float* Wk = (const float*)d_in[2];
  const float* Wv = (const float*)d_in[3];
  float* out = (float*)d_out;
  char* ws = (char*)d_ws;
  u16* qb  = (u16*)(ws);                    // 1 MB   : q bf16 [8192][64]
  u16* kb  = (u16*)(ws + (1u << 20));       // 1 MB   : k bf16 [8192][64]
  u16* vtb = (u16*)(ws + (2u << 20));       // 1 MB   : v^T bf16 tiled [4][32][64][64]
  u16* wtb = (u16*)(ws + (3u << 20));       // 384 KB : WT bf16 [3][64][1024]
  hipLaunchKernelGGL(wt_kernel,   dim3(48),  dim3(256), 0, stream, Wq, Wk, Wv, wtb);
  hipLaunchKernelGGL(proj_kernel, dim3(512), dim3(256), 0, stream, x, wtb, qb, kb, vtb);
  hipLaunchKernelGGL(attn_kernel, dim3(512), dim3(256), 0, stream, qb, kb, vtb, out);
}

// Round 12
// 40.300 us; speedup vs baseline: 2.5685x; 1.4112x over previous
//
#include <hip/hip_runtime.h>
#include <stdint.h>

#define NB 4
#define NT 2048
#define NC 1024
#define NH 64
#define NM (NB*NT)

typedef unsigned short u16;
typedef unsigned int u32;
typedef __bf16 bf16_t;
typedef float f32x4 __attribute__((ext_vector_type(4)));
typedef bf16_t bf16x8 __attribute__((ext_vector_type(8)));
typedef u16 u16x8 __attribute__((ext_vector_type(8)));
typedef u16 u16x4 __attribute__((ext_vector_type(4)));

__device__ __forceinline__ u16 f2b(float f) {
  return __builtin_bit_cast(u16, (bf16_t)f);
}
__device__ __forceinline__ float b2f(u16 u) {
  return (float)__builtin_bit_cast(bf16_t, u);
}

// async global->LDS 16B: LDS dest = WAVE-UNIFORM base + lane*16 (m104);
// per-lane swizzle folded into the GLOBAL source address (m173).
__device__ __forceinline__ void gl16(const void* g, void* l) {
  __builtin_amdgcn_global_load_lds(
      (const __attribute__((address_space(1))) u32*)g,
      (__attribute__((address_space(3))) u32*)l, 16, 0, 0);
}

// ---------------- Wq/Wk/Wv [1024][64] f32 -> WT [3][64][1024] bf16 (transposed)
__global__ __launch_bounds__(256) void wt_kernel(const float* __restrict__ Wq,
                                                 const float* __restrict__ Wk,
                                                 const float* __restrict__ Wv,
                                                 u16* __restrict__ wt) {
  __shared__ float t[64][65];
  const int m = blockIdx.x >> 4;
  const int kt = blockIdx.x & 15;
  const int k0 = kt * 64;
  const float* W = (m == 0) ? Wq : (m == 1) ? Wk : Wv;
  {
    const int r = threadIdx.x >> 2, c4 = threadIdx.x & 3;
    #pragma unroll
    for (int j = 0; j < 4; ++j) {
      const float4 f = *(const float4*)(W + (size_t)(k0 + r) * NH + c4 * 16 + j * 4);
      t[r][c4 * 16 + j * 4 + 0] = f.x;
      t[r][c4 * 16 + j * 4 + 1] = f.y;
      t[r][c4 * 16 + j * 4 + 2] = f.z;
      t[r][c4 * 16 + j * 4 + 3] = f.w;
    }
  }
  __syncthreads();
  const int n = threadIdx.x >> 2, kc = threadIdx.x & 3;
  u16x8 a, b;
  #pragma unroll
  for (int j = 0; j < 8; ++j) a[j] = f2b(t[kc * 16 + j][n]);
  #pragma unroll
  for (int j = 0; j < 8; ++j) b[j] = f2b(t[kc * 16 + 8 + j][n]);
  u16* dst = wt + ((size_t)(m * 64 + n)) * NC + k0 + kc * 16;
  *(u16x8*)dst = a;
  *(u16x8*)(dst + 8) = b;
}

// ---------------- fused QKV projection (r11, global_load_lds dbuf — unchanged)
__global__ __launch_bounds__(256, 2) void proj_kernel(const float* __restrict__ x,
                                                      const u16* __restrict__ wt,
                                                      u16* __restrict__ qo,
                                                      u16* __restrict__ ko,
                                                      u16* __restrict__ vto) {
  __shared__ float fA[2][16 * 64];
  __shared__ u16 sB[2][192 * 64];
  const int tid = threadIdx.x;
  const int lane = tid & 63;
  const int w = tid >> 6;
  const int g = lane >> 4;
  const int li = lane & 15;
  const int row0 = blockIdx.x * 16;
  const int wbase = tid & 0xC0;

  const f32x4 zero = {0.f, 0.f, 0.f, 0.f};
  f32x4 acc[3];
  #pragma unroll
  for (int i = 0; i < 3; ++i) acc[i] = zero;

  const int ar = tid >> 4;
  const int ac = tid & 15;
  const float* asrc0 = x + (size_t)(row0 + ar) * NC + ((ac ^ (ar & 7)) * 4);

  auto stage = [&](int kt, int nxt) {
    const int k0 = kt * 64;
    gl16(asrc0 + k0, (char*)fA[nxt] + wbase * 16);
    #pragma unroll
    for (int j = 0; j < 6; ++j) {
      const int cid = j * 256 + tid;
      const int n = cid >> 3, c = cid & 7;
      gl16(wt + (size_t)n * NC + k0 + ((c ^ (n & 7)) * 8),
           (char*)sB[nxt] + (j * 256 + wbase) * 16);
    }
  };

  stage(0, 0);
  __syncthreads();

  for (int kt = 0; kt < 16; ++kt) {
    const int cur = kt & 1;
    if (kt < 15) stage(kt + 1, cur ^ 1);
    #pragma unroll
    for (int ks = 0; ks < 2; ++ks) {
      const int c0 = ks * 8 + g * 2;
      const f32x4 a0 = *(const f32x4*)&fA[cur][li * 64 + ((c0 ^ (li & 7)) * 4)];
      const f32x4 a1 = *(const f32x4*)&fA[cur][li * 64 + (((c0 + 1) ^ (li & 7)) * 4)];
      bf16x8 a;
      a[0]=(bf16_t)a0.x; a[1]=(bf16_t)a0.y; a[2]=(bf16_t)a0.z; a[3]=(bf16_t)a0.w;
      a[4]=(bf16_t)a1.x; a[5]=(bf16_t)a1.y; a[6]=(bf16_t)a1.z; a[7]=(bf16_t)a1.w;
      #pragma unroll
      for (int f = 0; f < 3; ++f) {
        const int n = (w * 3 + f) * 16 + li;
        const bf16x8 b = *(const bf16x8*)&sB[cur][n * 64 + (((ks * 4 + g) ^ (n & 7)) * 8)];
        acc[f] = __builtin_amdgcn_mfma_f32_16x16x32_bf16(a, b, acc[f], 0, 0, 0);
      }
    }
    __syncthreads();
  }

  const int rr0 = row0 + g * 4;
  #pragma unroll
  for (int f = 0; f < 3; ++f) {
    const int fn = w * 3 + f;
    if (fn < 4) {
      #pragma unroll
      for (int i = 0; i < 4; ++i)
        qo[(size_t)(rr0 + i) * NH + fn * 16 + li] = f2b(acc[f][i]);
    } else if (fn < 8) {
      #pragma unroll
      for (int i = 0; i < 4; ++i)
        ko[(size_t)(rr0 + i) * NH + (fn - 4) * 16 + li] = f2b(acc[f][i]);
    } else {
      u16x4 pv;
      #pragma unroll
      for (int i = 0; i < 4; ++i) pv[i] = f2b(acc[f][i]);
      const int hs = (fn - 8) * 16 + li;
      const int bidx = rr0 >> 11;
      const int tt = rr0 & 2047;
      const int tile = tt >> 6, off = tt & 63;
      *(u16x4*)&vto[(((size_t)(bidx * 32 + tile) * 64) + hs) * 64 + off] = pv;
    }
  }
}

// ---------------- attention: diagonal-paired q-tiles (p, 63-p) => EXACTLY 33 kv-tiles
// per block; 8-way split S8 = z*2+ss over virtual tiles; full-width 64-kv PV;
// K/V staged via global_load_lds double-buffer per ss-group; static softmax;
// partials (8 splits) to global, exact-sum merge kernel.
__global__ __launch_bounds__(256, 2) void attn_kernel(const u16* __restrict__ qg,
                                                      const u16* __restrict__ kg,
                                                      const u16* __restrict__ vtg,
                                                      u16* __restrict__ pO,
                                                      float* __restrict__ pL) {
  __shared__ u16 sK[2][2][64 * 64];   // [ss][buf] 8KB tiles
  __shared__ u16 sV[2][2][64 * 64];
  __shared__ u16 sP[4][16 * 64];      // per-wave P
  const int tid = threadIdx.x;
  const int lane = tid & 63;
  const int wv = tid >> 6;
  const int qsub = wv & 1;
  const int ss = wv >> 1;
  const int g = lane >> 4;
  const int li = lane & 15;
  const int gtid = tid & 127;         // id within ss-group
  const int b = blockIdx.x;
  const int p = b & 31;
  const int bb = (b >> 5) & 3;
  const int z = b >> 7;               // 0..3
  const int S8 = z * 2 + ss;
  const size_t bt0 = (size_t)bb * NT;
  const int jtA = p, jtB = 63 - p;
  const int n1 = jtA / 2 + 1;         // kv tiles for tile A; total A+B = 33

  // Q fragments for both q-tiles
  bf16x8 aqA[2], aqB[2];
  #pragma unroll
  for (int ks = 0; ks < 2; ++ks) {
    aqA[ks] = *(const bf16x8*)(qg + (bt0 + jtA * 32 + qsub * 16 + li) * NH + ks * 32 + g * 8);
    aqB[ks] = *(const bf16x8*)(qg + (bt0 + jtB * 32 + qsub * 16 + li) * NH + ks * 32 + g * 8);
  }

  const f32x4 zero = {0.f, 0.f, 0.f, 0.f};
  f32x4 oA[4], oB[4];
  float lA[4], lB[4];
  #pragma unroll
  for (int i = 0; i < 4; ++i) { oA[i] = zero; oB[i] = zero; lA[i] = 0.f; lB[i] = 0.f; }

  // stage kv tile t (batch-local) into buf nb of this ss-group
  auto stage = [&](int t, int nb) {
    const size_t krow = bt0 + (size_t)t * 64;
    const size_t vrow = ((size_t)(bb * 32 + t)) * 64;
    #pragma unroll
    for (int j = 0; j < 4; ++j) {
      const int idx = j * 128 + gtid;
      const int n = idx >> 3, c = idx & 7;
      const int sc = (c ^ (n & 7)) * 8;
      const int dst = j * 2048 + qsub * 1024;     // wave-uniform
      gl16(kg + (krow + n) * NH + sc, (char*)sK[ss][nb] + dst);
      gl16(vtg + (vrow + n) * NH + sc, (char*)sV[ss][nb] + dst);
    }
  };

  auto computeT = [&](const bf16x8 (&aq)[2], f32x4 (&o)[4], float (&ls)[4],
                      int jt, int t, int buf) {
    const int kv0 = t * 64;
    const int q0w = jt * 32 + qsub * 16;
    f32x4 sc[4];
    #pragma unroll
    for (int fn = 0; fn < 4; ++fn) sc[fn] = zero;
    #pragma unroll
    for (int ks = 0; ks < 2; ++ks) {
      #pragma unroll
      for (int fn = 0; fn < 4; ++fn) {
        const int n = fn * 16 + li;
        const bf16x8 bk = *(const bf16x8*)&sK[ss][buf][n * 64 + (((ks * 4 + g) ^ (n & 7)) * 8)];
        sc[fn] = __builtin_amdgcn_mfma_f32_16x16x32_bf16(aq[ks], bk, sc[fn], 0, 0, 0);
      }
    }
    const bool needmask = (kv0 + 63 > q0w);
    #pragma unroll
    for (int fn = 0; fn < 4; ++fn) {
      #pragma unroll
      for (int i = 0; i < 4; ++i) {
        float v = sc[fn][i] * 0.125f;
        if (needmask && (kv0 + fn * 16 + li > q0w + g * 4 + i)) v = -1e30f;
        const float e = __expf(v);
        ls[i] += e;
        const int ql = g * 4 + i;
        const int kv = fn * 16 + li;
        sP[wv][ql * 64 + (((kv >> 3) ^ (ql & 7)) * 8) + (kv & 7)] = f2b(e);
      }
    }
    #pragma unroll
    for (int ks = 0; ks < 2; ++ks) {
      const bf16x8 pa = *(const bf16x8*)&sP[wv][li * 64 + (((ks * 4 + g) ^ (li & 7)) * 8)];
      #pragma unroll
      for (int fn = 0; fn < 4; ++fn) {
        const int n = fn * 16 + li;
        const bf16x8 bv = *(const bf16x8*)&sV[ss][buf][n * 64 + (((ks * 4 + g) ^ (n & 7)) * 8)];
        o[fn] = __builtin_amdgcn_mfma_f32_16x16x32_bf16(pa, bv, o[fn], 0, 0, 0);
      }
    }
  };

  // prologue: stage first virtual tile (S8 < 33 always)
  {
    const int v0 = S8;
    const int t0 = (v0 < n1) ? v0 : v0 - n1;
    stage(t0, 0);
  }
  __syncthreads();

  #pragma unroll 1
  for (int k = 0; k < 5; ++k) {
    const int v = S8 + 8 * k;
    const bool act = (v < 33);
    const int vn = v + 8;
    if (vn < 33) {
      const int tn = (vn < n1) ? vn : vn - n1;
      stage(tn, (k + 1) & 1);
    }
    if (act) {
      const int buf = k & 1;
      if (v < n1) computeT(aqA, oA, lA, jtA, v, buf);
      else        computeT(aqB, oB, lB, jtB, v - n1, buf);
    }
    __syncthreads();
  }

  // row-reduce l within 16-lane groups
  #pragma unroll
  for (int i = 0; i < 4; ++i) {
    float a = lA[i], c = lB[i];
    a += __shfl_xor(a, 1); c += __shfl_xor(c, 1);
    a += __shfl_xor(a, 2); c += __shfl_xor(c, 2);
    a += __shfl_xor(a, 4); c += __shfl_xor(c, 4);
    a += __shfl_xor(a, 8); c += __shfl_xor(c, 8);
    lA[i] = a; lB[i] = c;
  }

  // write partials for both q-tiles
  #pragma unroll
  for (int fn = 0; fn < 4; ++fn) {
    #pragma unroll
    for (int i = 0; i < 4; ++i) {
      const size_t rowA = bt0 + jtA * 32 + qsub * 16 + g * 4 + i;
      const size_t rowB = bt0 + jtB * 32 + qsub * 16 + g * 4 + i;
      pO[((size_t)S8 * NM + rowA) * NH + fn * 16 + li] = f2b(oA[fn][i]);
      pO[((size_t)S8 * NM + rowB) * NH + fn * 16 + li] = f2b(oB[fn][i]);
    }
  }
  if (li == 0) {
    #pragma unroll
    for (int i = 0; i < 4; ++i) {
      const size_t rowA = bt0 + jtA * 32 + qsub * 16 + g * 4 + i;
      const size_t rowB = bt0 + jtB * 32 + qsub * 16 + g * 4 + i;
      pL[(size_t)S8 * NM + rowA] = lA[i];
      pL[(size_t)S8 * NM + rowB] = lB[i];
    }
  }
}

// ---------------- merge 8 KV-splits per row: out = sum(o_s) / sum(l_s) (exact)
__global__ __launch_bounds__(256) void merge_kernel(const u16* __restrict__ pO,
                                                    const float* __restrict__ pL,
                                                    float* __restrict__ out) {
  const int gid = blockIdx.x * 256 + threadIdx.x;
  const int row = gid >> 4;
  const int c0 = (gid & 15) * 4;
  float L = 0.f;
  #pragma unroll
  for (int s = 0; s < 8; ++s) L += pL[(size_t)s * NM + row];
  float acc0 = 0.f, acc1 = 0.f, acc2 = 0.f, acc3 = 0.f;
  #pragma unroll
  for (int s = 0; s < 8; ++s) {
    const u16x4 v = *(const u16x4*)&pO[((size_t)s * NM + row) * NH + c0];
    acc0 += b2f(v[0]);
    acc1 += b2f(v[1]);
    acc2 += b2f(v[2]);
    acc3 += b2f(v[3]);
  }
  const float inv = 1.f / L;
  float4 rr = {acc0 * inv, acc1 * inv, acc2 * inv, acc3 * inv};
  *(float4*)&out[(size_t)row * NH + c0] = rr;
}

extern "C" void kernel_launch(void* const* d_in, const int* in_sizes, int n_in,
                              void* d_out, int out_size, void* d_ws, size_t ws_size,
                              hipStream_t stream) {
  (void)in_sizes; (void)n_in; (void)out_size; (void)ws_size;
  const float* x  = (const float*)d_in[0];
  const float* Wq = (const float*)d_in[1];
  const float* Wk = (const float*)d_in[2];
  const float* Wv = (const float*)d_in[3];
  float* out = (float*)d_out;
  char* ws = (char*)d_ws;
  u16* qb   = (u16*)(ws);                    // 1 MB   : q bf16 [8192][64]
  u16* kb   = (u16*)(ws + (1u << 20));       // 1 MB   : k bf16 [8192][64]
  u16* vtb  = (u16*)(ws + (2u << 20));       // 1 MB   : v^T bf16 tiled [4][32][64][64]
  u16* wtb  = (u16*)(ws + (3u << 20));       // 384 KB : WT bf16 [3][64][1024]
  u16* pO   = (u16*)(ws + (4u << 20));       // 8 MB   : partial O bf16 [8][8192][64]
  float* pL = (float*)(ws + (12u << 20));    // 256 KB : partial l f32 [8][8192]
  hipLaunchKernelGGL(wt_kernel,    dim3(48),  dim3(256), 0, stream, Wq, Wk, Wv, wtb);
  hipLaunchKernelGGL(proj_kernel,  dim3(512), dim3(256), 0, stream, x, wtb, qb, kb, vtb);
  hipLaunchKernelGGL(attn_kernel,  dim3(512), dim3(256), 0, stream, qb, kb, vtb, pO, pL);
  hipLaunchKernelGGL(merge_kernel, dim3(512), dim3(256), 0, stream, pO, pL, out);
}

// Round 13
// 38.452 us; speedup vs baseline: 2.6919x; 1.0481x over previous
//
#include <hip/hip_runtime.h>
#include <stdint.h>

#define NB 4
#define NT 2048
#define NC 1024
#define NH 64
#define NM (NB*NT)

typedef unsigned short u16;
typedef unsigned int u32;
typedef __bf16 bf16_t;
typedef float f32x4 __attribute__((ext_vector_type(4)));
typedef bf16_t bf16x8 __attribute__((ext_vector_type(8)));
typedef u16 u16x8 __attribute__((ext_vector_type(8)));
typedef u16 u16x4 __attribute__((ext_vector_type(4)));

__device__ __forceinline__ u16 f2b(float f) {
  return __builtin_bit_cast(u16, (bf16_t)f);
}

// async global->LDS 16B: LDS dest = WAVE-UNIFORM base + lane*16 (m104);
// per-lane swizzle folded into the GLOBAL source address (m173).
__device__ __forceinline__ void gl16(const void* g, void* l) {
  __builtin_amdgcn_global_load_lds(
      (const __attribute__((address_space(1))) u32*)g,
      (__attribute__((address_space(3))) u32*)l, 16, 0, 0);
}

// ---------------- Wq/Wk/Wv [1024][64] f32 -> WT [3][64][1024] bf16 (transposed)
__global__ __launch_bounds__(256) void wt_kernel(const float* __restrict__ Wq,
                                                 const float* __restrict__ Wk,
                                                 const float* __restrict__ Wv,
                                                 u16* __restrict__ wt) {
  __shared__ float t[64][65];
  const int m = blockIdx.x >> 4;
  const int kt = blockIdx.x & 15;
  const int k0 = kt * 64;
  const float* W = (m == 0) ? Wq : (m == 1) ? Wk : Wv;
  {
    const int r = threadIdx.x >> 2, c4 = threadIdx.x & 3;
    #pragma unroll
    for (int j = 0; j < 4; ++j) {
      const float4 f = *(const float4*)(W + (size_t)(k0 + r) * NH + c4 * 16 + j * 4);
      t[r][c4 * 16 + j * 4 + 0] = f.x;
      t[r][c4 * 16 + j * 4 + 1] = f.y;
      t[r][c4 * 16 + j * 4 + 2] = f.z;
      t[r][c4 * 16 + j * 4 + 3] = f.w;
    }
  }
  __syncthreads();
  const int n = threadIdx.x >> 2, kc = threadIdx.x & 3;
  u16x8 a, b;
  #pragma unroll
  for (int j = 0; j < 8; ++j) a[j] = f2b(t[kc * 16 + j][n]);
  #pragma unroll
  for (int j = 0; j < 8; ++j) b[j] = f2b(t[kc * 16 + 8 + j][n]);
  u16* dst = wt + ((size_t)(m * 64 + n)) * NC + k0 + kc * 16;
  *(u16x8*)dst = a;
  *(u16x8*)(dst + 8) = b;
}

// ---------------- fused QKV projection (r11/r12, global_load_lds dbuf — unchanged)
__global__ __launch_bounds__(256, 2) void proj_kernel(const float* __restrict__ x,
                                                      const u16* __restrict__ wt,
                                                      u16* __restrict__ qo,
                                                      u16* __restrict__ ko,
                                                      u16* __restrict__ vto) {
  __shared__ float fA[2][16 * 64];
  __shared__ u16 sB[2][192 * 64];
  const int tid = threadIdx.x;
  const int lane = tid & 63;
  const int w = tid >> 6;
  const int g = lane >> 4;
  const int li = lane & 15;
  const int row0 = blockIdx.x * 16;
  const int wbase = tid & 0xC0;

  const f32x4 zero = {0.f, 0.f, 0.f, 0.f};
  f32x4 acc[3];
  #pragma unroll
  for (int i = 0; i < 3; ++i) acc[i] = zero;

  const int ar = tid >> 4;
  const int ac = tid & 15;
  const float* asrc0 = x + (size_t)(row0 + ar) * NC + ((ac ^ (ar & 7)) * 4);

  auto stage = [&](int kt, int nxt) {
    const int k0 = kt * 64;
    gl16(asrc0 + k0, (char*)fA[nxt] + wbase * 16);
    #pragma unroll
    for (int j = 0; j < 6; ++j) {
      const int cid = j * 256 + tid;
      const int n = cid >> 3, c = cid & 7;
      gl16(wt + (size_t)n * NC + k0 + ((c ^ (n & 7)) * 8),
           (char*)sB[nxt] + (j * 256 + wbase) * 16);
    }
  };

  stage(0, 0);
  __syncthreads();

  for (int kt = 0; kt < 16; ++kt) {
    const int cur = kt & 1;
    if (kt < 15) stage(kt + 1, cur ^ 1);
    #pragma unroll
    for (int ks = 0; ks < 2; ++ks) {
      const int c0 = ks * 8 + g * 2;
      const f32x4 a0 = *(const f32x4*)&fA[cur][li * 64 + ((c0 ^ (li & 7)) * 4)];
      const f32x4 a1 = *(const f32x4*)&fA[cur][li * 64 + (((c0 + 1) ^ (li & 7)) * 4)];
      bf16x8 a;
      a[0]=(bf16_t)a0.x; a[1]=(bf16_t)a0.y; a[2]=(bf16_t)a0.z; a[3]=(bf16_t)a0.w;
      a[4]=(bf16_t)a1.x; a[5]=(bf16_t)a1.y; a[6]=(bf16_t)a1.z; a[7]=(bf16_t)a1.w;
      #pragma unroll
      for (int f = 0; f < 3; ++f) {
        const int n = (w * 3 + f) * 16 + li;
        const bf16x8 b = *(const bf16x8*)&sB[cur][n * 64 + (((ks * 4 + g) ^ (n & 7)) * 8)];
        acc[f] = __builtin_amdgcn_mfma_f32_16x16x32_bf16(a, b, acc[f], 0, 0, 0);
      }
    }
    __syncthreads();
  }

  const int rr0 = row0 + g * 4;
  #pragma unroll
  for (int f = 0; f < 3; ++f) {
    const int fn = w * 3 + f;
    if (fn < 4) {
      #pragma unroll
      for (int i = 0; i < 4; ++i)
        qo[(size_t)(rr0 + i) * NH + fn * 16 + li] = f2b(acc[f][i]);
    } else if (fn < 8) {
      #pragma unroll
      for (int i = 0; i < 4; ++i)
        ko[(size_t)(rr0 + i) * NH + (fn - 4) * 16 + li] = f2b(acc[f][i]);
    } else {
      u16x4 pv;
      #pragma unroll
      for (int i = 0; i < 4; ++i) pv[i] = f2b(acc[f][i]);
      const int hs = (fn - 8) * 16 + li;
      const int bidx = rr0 >> 11;
      const int tt = rr0 & 2047;
      const int tile = tt >> 6, off = tt & 63;
      *(u16x4*)&vto[(((size_t)(bidx * 32 + tile) * 64) + hs) * 64 + off] = pv;
    }
  }
}

// ---------------- attention: pair (j, 127-j) of 16-row q-tiles => EXACTLY 65 kv-tiles
// (32-wide) per block. 8 waves = 8 kv-splits, each with PRIVATE K/V LDS dbuf staged
// via global_load_lds + hand-counted vmcnt — NO barriers in the loop. Static softmax;
// in-block exact-sum merge; out written directly (no merge kernel, no partials).
struct AttnGrp {
  union {
    struct { u16 K[2][32 * 64]; u16 V[2][64 * 32]; } st;  // 16 KB
    struct { float mo[2][16][64]; float ml[2][16]; } mg;  // 8.3 KB (aliased after loop)
  } u;
};

__global__ __launch_bounds__(512) void attn_kernel(const u16* __restrict__ qg,
                                                   const u16* __restrict__ kg,
                                                   const u16* __restrict__ vtg,
                                                   float* __restrict__ out) {
  __shared__ AttnGrp grp[8];          // 128 KB
  __shared__ u16 sP[8][16 * 32];      // 8 KB per-wave P tiles
  const int tid = threadIdx.x;
  const int lane = tid & 63;
  const int s = tid >> 3 >> 3;        // wave = kv split 0..7
  const int g = lane >> 4;
  const int li = lane & 15;
  const int jA = blockIdx.x & 63;
  const int bb = blockIdx.x >> 6;
  const int jB = 127 - jA;
  const size_t bt0 = (size_t)bb * NT;
  const int q0A = jA * 16, q0B = jB * 16;
  const int n1 = (jA >> 1) + 1;       // kv tiles (32-wide) for tile A; A+B = 65 always

  // Q fragments for both q-tiles
  bf16x8 aqA[2], aqB[2];
  #pragma unroll
  for (int ks = 0; ks < 2; ++ks) {
    aqA[ks] = *(const bf16x8*)(qg + (bt0 + q0A + li) * NH + ks * 32 + g * 8);
    aqB[ks] = *(const bf16x8*)(qg + (bt0 + q0B + li) * NH + ks * 32 + g * 8);
  }

  const f32x4 zero = {0.f, 0.f, 0.f, 0.f};
  f32x4 oA[4], oB[4];
  float lA[4], lB[4];
  #pragma unroll
  for (int i = 0; i < 4; ++i) { oA[i] = zero; oB[i] = zero; lA[i] = 0.f; lB[i] = 0.f; }

  // stage virtual tile v into buf b (exactly 8 gl16 per call, wave-private)
  auto stage = [&](int v, int b) {
    const int kvt = (v < n1) ? v : v - n1;
    const size_t kbase = bt0 + (size_t)kvt * 32;
    #pragma unroll
    for (int jj = 0; jj < 4; ++jj) {
      const int idx = jj * 64 + lane;
      const int n = idx >> 3, c = idx & 7;
      gl16(kg + (kbase + n) * NH + ((c ^ (n & 7)) * 8),
           (char*)grp[s].u.st.K[b] + jj * 1024);
    }
    const size_t vbase = ((size_t)(bb * 32 + (kvt >> 1))) * 64;
    const int hoff = (kvt & 1) * 32;
    #pragma unroll
    for (int jj = 0; jj < 4; ++jj) {
      const int idx = jj * 64 + lane;
      const int n = idx >> 2, c = idx & 3;
      gl16(vtg + (vbase + n) * 64 + hoff + ((c ^ (n & 3) ^ ((n >> 2) & 3)) * 8),
           (char*)grp[s].u.st.V[b] + jj * 1024);
    }
  };

  auto computeT = [&](const bf16x8 (&aq)[2], f32x4 (&o)[4], float (&ls)[4],
                      int q0, int kv0, int b) {
    // QK^T: S[16q][32kv], k-dim = hs = 64
    f32x4 sc2[2] = {zero, zero};
    #pragma unroll
    for (int ks = 0; ks < 2; ++ks) {
      #pragma unroll
      for (int fn = 0; fn < 2; ++fn) {
        const int n = fn * 16 + li;
        const bf16x8 bk = *(const bf16x8*)&grp[s].u.st.K[b][n * 64 + (((ks * 4 + g) ^ (n & 7)) * 8)];
        sc2[fn] = __builtin_amdgcn_mfma_f32_16x16x32_bf16(aq[ks], bk, sc2[fn], 0, 0, 0);
      }
    }
    // static softmax: P = exp(s/8); masked -> 0
    const bool needmask = (kv0 + 31 > q0);
    #pragma unroll
    for (int fn = 0; fn < 2; ++fn) {
      #pragma unroll
      for (int i = 0; i < 4; ++i) {
        const int q = g * 4 + i;
        float v = sc2[fn][i] * 0.125f;
        if (needmask && (kv0 + fn * 16 + li > q0 + q)) v = -1e30f;
        const float e = __expf(v);
        ls[i] += e;
        const int kc = fn * 2 + (li >> 3);
        sP[s][q * 32 + ((kc ^ (q & 3) ^ ((q >> 2) & 3)) * 8) + (li & 7)] = f2b(e);
      }
    }
    // PV: o[16q][64hs] += P[16q][32kv] * V[32kv][64hs]
    const bf16x8 pa = *(const bf16x8*)&sP[s][li * 32 + ((g ^ (li & 3) ^ ((li >> 2) & 3)) * 8)];
    #pragma unroll
    for (int fn = 0; fn < 4; ++fn) {
      const int n = fn * 16 + li;
      const bf16x8 bv = *(const bf16x8*)&grp[s].u.st.V[b][n * 32 + ((g ^ (n & 3) ^ ((n >> 2) & 3)) * 8)];
      o[fn] = __builtin_amdgcn_mfma_f32_16x16x32_bf16(pa, bv, o[fn], 0, 0, 0);
    }
  };

  // main loop: wave-private, barrier-free; vmcnt(8) = previous tile resident
  const int nt = (64 - s) / 8 + 1;    // 65 tiles: split s gets 8 or 9
  int v = s;
  stage(v, 0);
  for (int k = 0; k < nt; ++k) {
    if (k + 1 < nt) {
      stage(v + 8, (k + 1) & 1);
      asm volatile("s_waitcnt vmcnt(8)" ::: "memory");
    } else {
      asm volatile("s_waitcnt vmcnt(0)" ::: "memory");
    }
    const int b = k & 1;
    if (v < n1) computeT(aqA, oA, lA, q0A, v * 32, b);
    else        computeT(aqB, oB, lB, q0B, (v - n1) * 32, b);
    v += 8;
  }

  // row-reduce l over li (16-lane groups)
  #pragma unroll
  for (int i = 0; i < 4; ++i) {
    float a = lA[i], c = lB[i];
    a += __shfl_xor(a, 1); c += __shfl_xor(c, 1);
    a += __shfl_xor(a, 2); c += __shfl_xor(c, 2);
    a += __shfl_xor(a, 4); c += __shfl_xor(c, 4);
    a += __shfl_xor(a, 8); c += __shfl_xor(c, 8);
    lA[i] = a; lB[i] = c;
  }

  // write partials to THIS GROUP's LDS region (safe: wave-private alias)
  #pragma unroll
  for (int fn = 0; fn < 4; ++fn) {
    #pragma unroll
    for (int i = 0; i < 4; ++i) {
      grp[s].u.mg.mo[0][g * 4 + i][fn * 16 + li] = oA[fn][i];
      grp[s].u.mg.mo[1][g * 4 + i][fn * 16 + li] = oB[fn][i];
    }
  }
  if (li == 0) {
    #pragma unroll
    for (int i = 0; i < 4; ++i) {
      grp[s].u.mg.ml[0][g * 4 + i] = lA[i];
      grp[s].u.mg.ml[1][g * 4 + i] = lB[i];
    }
  }
  __syncthreads();

  // combine 8 splits, write out (2048 f32 per block, 4 consecutive per thread)
  {
    const int base = tid * 4;
    const int tile = base >> 10;
    const int r = (base >> 6) & 15;
    const int c0 = base & 63;
    float L = 0.f;
    f32x4 acc = zero;
    #pragma unroll
    for (int s8 = 0; s8 < 8; ++s8) {
      L += grp[s8].u.mg.ml[tile][r];
      acc += *(const f32x4*)&grp[s8].u.mg.mo[tile][r][c0];
    }
    const int row = (tile ? q0B : q0A) + r;
    const float inv = 1.f / L;
    acc *= inv;
    *(f32x4*)&out[(bt0 + row) * NH + c0] = acc;
  }
}

extern "C" void kernel_launch(void* const* d_in, const int* in_sizes, int n_in,
                              void* d_out, int out_size, void* d_ws, size_t ws_size,
                              hipStream_t stream) {
  (void)in_sizes; (void)n_in; (void)out_size; (void)ws_size;
  const float* x  = (const float*)d_in[0];
  const float* Wq = (const float*)d_in[1];
  const float* Wk = (const float*)d_in[2];
  const float* Wv = (const float*)d_in[3];
  float* out = (float*)d_out;
  char* ws = (char*)d_ws;
  u16* qb  = (u16*)(ws);                    // 1 MB   : q bf16 [8192][64]
  u16* kb  = (u16*)(ws + (1u << 20));       // 1 MB   : k bf16 [8192][64]
  u16* vtb = (u16*)(ws + (2u << 20));       // 1 MB   : v^T bf16 tiled [4][32][64][64]
  u16* wtb = (u16*)(ws + (3u << 20));       // 384 KB : WT bf16 [3][64][1024]
  hipLaunchKernelGGL(wt_kernel,   dim3(48),  dim3(256), 0, stream, Wq, Wk, Wv, wtb);
  hipLaunchKernelGGL(proj_kernel, dim3(512), dim3(256), 0, stream, x, wtb, qb, kb, vtb);
  hipLaunchKernelGGL(attn_kernel, dim3(256), dim3(512), 0, stream, qb, kb, vtb, out);
}